// Round 16
// baseline (117.240 us; speedup 1.0000x reference)
//
#include <hip/hip_runtime.h>

#define BT 16384
#define DK 4096
#define NE 64
#define BM 64                 // rows per block -> grid 256
#define NSTG 16               // stages of 256 k-floats
#define NPROBS (BT * NE)
#define NIDX (NPROBS)
#define NWTS (NPROBS + BT * 2)

typedef __bf16 bf16x8 __attribute__((ext_vector_type(8)));
typedef float f32x4 __attribute__((ext_vector_type(4)));

__device__ __forceinline__ unsigned asu(float f) { return __builtin_bit_cast(unsigned, f); }
__device__ __forceinline__ float asf(unsigned u) { return __builtin_bit_cast(float, u); }

// async global->LDS, 16B per lane; lds dest = base + lane*16 (linear)
__device__ __forceinline__ void gl_lds16(const void* g, void* l) {
    __builtin_amdgcn_global_load_lds(
        (const __attribute__((address_space(1))) unsigned int*)g,
        (__attribute__((address_space(3))) unsigned int*)l, 16, 0, 0);
}

// Split 8 f32 into 3 bf16 planes (truncation split; residuals exact in f32).
__device__ __forceinline__ void split3(const float* xx, uint4* pl) {
    unsigned h0[8], h1[8], h2[8];
#pragma unroll
    for (int j = 0; j < 8; ++j) {
        const float xf = xx[j];
        const unsigned a0 = asu(xf) & 0xFFFF0000u;
        const float r1 = xf - asf(a0);
        const unsigned a1 = asu(r1) & 0xFFFF0000u;
        const float r2 = r1 - asf(a1);
        const unsigned a2 = asu(r2) & 0xFFFF0000u;
        h0[j] = a0; h1[j] = a1; h2[j] = a2;
    }
    pl[0] = make_uint4((h0[0] >> 16) | (h0[1] & 0xFFFF0000u), (h0[2] >> 16) | (h0[3] & 0xFFFF0000u),
                       (h0[4] >> 16) | (h0[5] & 0xFFFF0000u), (h0[6] >> 16) | (h0[7] & 0xFFFF0000u));
    pl[1] = make_uint4((h1[0] >> 16) | (h1[1] & 0xFFFF0000u), (h1[2] >> 16) | (h1[3] & 0xFFFF0000u),
                       (h1[4] >> 16) | (h1[5] & 0xFFFF0000u), (h1[6] >> 16) | (h1[7] & 0xFFFF0000u));
    pl[2] = make_uint4((h2[0] >> 16) | (h2[1] & 0xFFFF0000u), (h2[2] >> 16) | (h2[3] & 0xFFFF0000u),
                       (h2[4] >> 16) | (h2[5] & 0xFFFF0000u), (h2[6] >> 16) | (h2[7] & 0xFFFF0000u));
}

// prep: W (64 x 4096 f32) -> 3 bf16 planes in B-fragment order (validated R11+).
__global__ __launch_bounds__(256) void w_prep(
    const float* __restrict__ W, uint4* __restrict__ WF)
{
    const int g  = blockIdx.x * 256 + threadIdx.x;
    const int e  = g >> 9;
    const int kg = g & 511;
    const float4 v0 = *(const float4*)(W + (long)e * DK + kg * 8);
    const float4 v1 = *(const float4*)(W + (long)e * DK + kg * 8 + 4);
    float xx[8] = {v0.x, v0.y, v0.z, v0.w, v1.x, v1.y, v1.z, v1.w};
    uint4 pl[3];
    split3(xx, pl);
    const int ks = kg >> 2;
    const int l  = (e & 15) | ((kg & 3) << 4);
    const int et = e >> 4;
#pragma unroll
    for (int p = 0; p < 3; ++p)
        WF[((ks * 4 + et) * 3 + p) * 64 + l] = pl[p];
}

// Main: 256 blocks x 64 rows, 8 waves = eh(2) x rq(4). No split-K.
// X: staged coalesced via global_load_lds (ONE contiguous 1KB row-segment per
// inst -- kills the 16-line 16KB-stride gather that capped R11-R15 at 114us).
// Swizzle via pre-swizzled global source (lane^i), linear LDS dest; reader
// XORs (r&7). B: frag-ordered WF (validated). 12 MFMA / substep / wave.
__global__ __launch_bounds__(512) void token_router(
    const float* __restrict__ x, const uint4* __restrict__ WF,
    float* __restrict__ out)
{
    __shared__ float4 xs4[2][BM][64];        // 128 KB, double-buffered X tile
    __shared__ float  lg[BM * 68 + 2 * BM];  // 17.5 KB logits + rowm/rowinv

    const int tid  = threadIdx.x;
    const int wv   = tid >> 6;
    const int lane = tid & 63;
    const int eh   = wv & 1;          // expert half
    const int rq   = wv >> 1;         // row-tile 0..3
    const long rowbase = (long)blockIdx.x * BM;

    // staging source: wave wv owns rows wv*8..wv*8+7; lane reads global unit
    // (lane ^ i) of the row's 1KB chunk -> LDS slot lane (linear dest).
    const float* gst = x + (rowbase + wv * 8) * (long)DK;

    // A-frag read coords: row rl in tile, k-octet o; swizzle = rl&7
    const int rl  = lane & 15;
    const int o2  = (lane >> 4) * 2;          // unit pair base
    const int swz = rl & 7;
    const float4* arow = &xs4[0][rq * 16 + rl][0];   // + buf*4096 + slot

    // B base for this lane
    const uint4* wfs = WF + lane;

    f32x4 acc0 = {0.f, 0.f, 0.f, 0.f};
    f32x4 acc1 = {0.f, 0.f, 0.f, 0.f};

    // prologue: stage 0 -> buf 0
#pragma unroll
    for (int i = 0; i < 8; ++i)
        gl_lds16(gst + i * (long)DK + ((lane ^ i) << 2), &xs4[0][wv * 8 + i][0]);
    __syncthreads();

    for (int s = 0; s < NSTG; ++s) {
        const int buf = (s & 1) * 4096;      // float4 offset into xs4
#pragma unroll
        for (int ks = 0; ks < 8; ++ks) {
            // B fragments for k-group s*8+ks, experts (2eh)*16.. and (2eh+1)*16..
            uint4 b0[3], b1[3];
#pragma unroll
            for (int p = 0; p < 3; ++p) {
                b0[p] = wfs[(ks * 12 + (2 * eh + 0) * 3 + p) * 64];
                b1[p] = wfs[(ks * 12 + (2 * eh + 1) * 3 + p) * 64];
            }
            // A: 8 f32 from LDS (swizzled slots), split to 3 bf16 planes
            const float4 alo = arow[buf + ks * 8 + ((o2 + 0) ^ swz)];
            const float4 ahi = arow[buf + ks * 8 + ((o2 + 1) ^ swz)];
            float xx[8] = {alo.x, alo.y, alo.z, alo.w, ahi.x, ahi.y, ahi.z, ahi.w};
            uint4 pl[3];
            split3(xx, pl);
            const bf16x8 A0 = __builtin_bit_cast(bf16x8, pl[0]);
            const bf16x8 A1 = __builtin_bit_cast(bf16x8, pl[1]);
            const bf16x8 A2 = __builtin_bit_cast(bf16x8, pl[2]);
            {
                const bf16x8 B0 = __builtin_bit_cast(bf16x8, b0[0]);
                const bf16x8 B1 = __builtin_bit_cast(bf16x8, b0[1]);
                const bf16x8 B2 = __builtin_bit_cast(bf16x8, b0[2]);
                acc0 = __builtin_amdgcn_mfma_f32_16x16x32_bf16(A0, B0, acc0, 0, 0, 0);
                acc0 = __builtin_amdgcn_mfma_f32_16x16x32_bf16(A0, B1, acc0, 0, 0, 0);
                acc0 = __builtin_amdgcn_mfma_f32_16x16x32_bf16(A1, B0, acc0, 0, 0, 0);
                acc0 = __builtin_amdgcn_mfma_f32_16x16x32_bf16(A1, B1, acc0, 0, 0, 0);
                acc0 = __builtin_amdgcn_mfma_f32_16x16x32_bf16(A0, B2, acc0, 0, 0, 0);
                acc0 = __builtin_amdgcn_mfma_f32_16x16x32_bf16(A2, B0, acc0, 0, 0, 0);
            }
            {
                const bf16x8 B0 = __builtin_bit_cast(bf16x8, b1[0]);
                const bf16x8 B1 = __builtin_bit_cast(bf16x8, b1[1]);
                const bf16x8 B2 = __builtin_bit_cast(bf16x8, b1[2]);
                acc1 = __builtin_amdgcn_mfma_f32_16x16x32_bf16(A0, B0, acc1, 0, 0, 0);
                acc1 = __builtin_amdgcn_mfma_f32_16x16x32_bf16(A0, B1, acc1, 0, 0, 0);
                acc1 = __builtin_amdgcn_mfma_f32_16x16x32_bf16(A1, B0, acc1, 0, 0, 0);
                acc1 = __builtin_amdgcn_mfma_f32_16x16x32_bf16(A1, B1, acc1, 0, 0, 0);
                acc1 = __builtin_amdgcn_mfma_f32_16x16x32_bf16(A0, B2, acc1, 0, 0, 0);
                acc1 = __builtin_amdgcn_mfma_f32_16x16x32_bf16(A2, B0, acc1, 0, 0, 0);
            }
        }
        // stage s+1 into the other buffer; issued AFTER all this stage's B
        // loads so B-waits never drained staging; the barrier's vmcnt(0)
        // is the single drain point per stage.
        if (s + 1 < NSTG) {
            const float* gn = gst + (s + 1) * 256;
            float4* ld = &xs4[(s & 1) ^ 1][wv * 8][0];
#pragma unroll
            for (int i = 0; i < 8; ++i)
                gl_lds16(gn + i * (long)DK + ((lane ^ i) << 2), ld + i * 64);
        }
        wfs += 6144;   // 8 k-groups * 12 * 64 uint4
        __syncthreads();
    }

    // ---- logits to LDS (C/D: col = lane&15, row = (lane>>4)*4 + jj) ----
#pragma unroll
    for (int jj = 0; jj < 4; ++jj) {
        const int row = rq * 16 + (lane >> 4) * 4 + jj;
        lg[row * 68 + (2 * eh + 0) * 16 + (lane & 15)] = acc0[jj];
        lg[row * 68 + (2 * eh + 1) * 16 + (lane & 15)] = acc1[jj];
    }
    __syncthreads();

    // ---- per-row softmax stats + stable top-2 (one thread per row) ----
    float* rowm   = lg + BM * 68;
    float* rowinv = rowm + BM;
    if (tid < BM) {
        const int row = tid;
        float m = -3.4e38f;
        for (int e = 0; e < NE; ++e) m = fmaxf(m, lg[row * 68 + e]);
        float s = 0.f;
        float v1 = -1.f, v2 = -1.f;
        int   i1 = 0,    i2 = 0;
        for (int e = 0; e < NE; ++e) {
            const float p = __expf(lg[row * 68 + e] - m);
            s += p;
            if (p > v1)      { v2 = v1; i2 = i1; v1 = p; i1 = e; }
            else if (p > v2) { v2 = p; i2 = e; }
        }
        const float inv = 1.f / s;
        rowm[row]   = m;
        rowinv[row] = inv;
        const long grow = rowbase + row;
        const float p1 = v1 * inv, p2 = v2 * inv;
        const float dn = p1 + p2 + 1e-9f;
        out[NIDX + grow * 2 + 0] = (float)i1;
        out[NIDX + grow * 2 + 1] = (float)i2;
        out[NWTS + grow * 2 + 0] = p1 / dn;
        out[NWTS + grow * 2 + 1] = p2 / dn;
    }
    __syncthreads();

    // ---- probs write: 512 threads x 8 floats, coalesced ----
    {
        const int row = tid >> 3;
        const int e0  = (tid & 7) << 3;
        const float m = rowm[row], inv = rowinv[row];
        const long grow = rowbase + row;
        const float4 l4a = *reinterpret_cast<const float4*>(&lg[row * 68 + e0]);
        const float4 l4b = *reinterpret_cast<const float4*>(&lg[row * 68 + e0 + 4]);
        float4 p0, p1;
        p0.x = __expf(l4a.x - m) * inv;
        p0.y = __expf(l4a.y - m) * inv;
        p0.z = __expf(l4a.z - m) * inv;
        p0.w = __expf(l4a.w - m) * inv;
        p1.x = __expf(l4b.x - m) * inv;
        p1.y = __expf(l4b.y - m) * inv;
        p1.z = __expf(l4b.z - m) * inv;
        p1.w = __expf(l4b.w - m) * inv;
        *reinterpret_cast<float4*>(&out[grow * (long)NE + e0])     = p0;
        *reinterpret_cast<float4*>(&out[grow * (long)NE + e0 + 4]) = p1;
    }
}

extern "C" void kernel_launch(void* const* d_in, const int* in_sizes, int n_in,
                              void* d_out, int out_size, void* d_ws, size_t ws_size,
                              hipStream_t stream) {
    const float* x = (const float*)d_in[0];
    const float* W = (const float*)d_in[1];
    float* out = (float*)d_out;
    uint4* WF  = (uint4*)d_ws;   // 1.5 MB fragment-ordered W planes

    w_prep<<<dim3(128), dim3(256), 0, stream>>>(W, WF);
    token_router<<<dim3(BT / BM), dim3(512), 0, stream>>>(x, WF, out);
}

// Round 17
// 100.134 us; speedup vs baseline: 1.1708x; 1.1708x over previous
//
#include <hip/hip_runtime.h>

#define BT 16384
#define DK 4096
#define NE 64
#define BM 64                 // rows per block -> grid 256
#define NSTG 32               // stages of 128 k
#define NPROBS (BT * NE)
#define NIDX (NPROBS)
#define NWTS (NPROBS + BT * 2)

typedef __bf16 bf16x8 __attribute__((ext_vector_type(8)));
typedef float f32x4 __attribute__((ext_vector_type(4)));

__device__ __forceinline__ unsigned asu(float f) { return __builtin_bit_cast(unsigned, f); }
__device__ __forceinline__ float asf(unsigned u) { return __builtin_bit_cast(float, u); }

__device__ __forceinline__ void gl_lds16(const void* g, void* l) {
    __builtin_amdgcn_global_load_lds(
        (const __attribute__((address_space(1))) unsigned int*)g,
        (__attribute__((address_space(3))) unsigned int*)l, 16, 0, 0);
}

// Split 8 f32 into 3 bf16 planes (truncation split; residuals exact in f32).
__device__ __forceinline__ void split3(const float* xx, uint4* pl) {
    unsigned h0[8], h1[8], h2[8];
#pragma unroll
    for (int j = 0; j < 8; ++j) {
        const float xf = xx[j];
        const unsigned a0 = asu(xf) & 0xFFFF0000u;
        const float r1 = xf - asf(a0);
        const unsigned a1 = asu(r1) & 0xFFFF0000u;
        const float r2 = r1 - asf(a1);
        const unsigned a2 = asu(r2) & 0xFFFF0000u;
        h0[j] = a0; h1[j] = a1; h2[j] = a2;
    }
    pl[0] = make_uint4((h0[0] >> 16) | (h0[1] & 0xFFFF0000u), (h0[2] >> 16) | (h0[3] & 0xFFFF0000u),
                       (h0[4] >> 16) | (h0[5] & 0xFFFF0000u), (h0[6] >> 16) | (h0[7] & 0xFFFF0000u));
    pl[1] = make_uint4((h1[0] >> 16) | (h1[1] & 0xFFFF0000u), (h1[2] >> 16) | (h1[3] & 0xFFFF0000u),
                       (h1[4] >> 16) | (h1[5] & 0xFFFF0000u), (h1[6] >> 16) | (h1[7] & 0xFFFF0000u));
    pl[2] = make_uint4((h2[0] >> 16) | (h2[1] & 0xFFFF0000u), (h2[2] >> 16) | (h2[3] & 0xFFFF0000u),
                       (h2[4] >> 16) | (h2[5] & 0xFFFF0000u), (h2[6] >> 16) | (h2[7] & 0xFFFF0000u));
}

// prep: W (64 x 4096 f32) -> 3 bf16 planes in B-fragment order (validated R11+).
// WF linear idx = ks*768 + (et*3+p)*64 + l  (ks = k-group 0..127, et 0..3)
__global__ __launch_bounds__(256) void w_prep(
    const float* __restrict__ W, uint4* __restrict__ WF)
{
    const int g  = blockIdx.x * 256 + threadIdx.x;
    const int e  = g >> 9;
    const int kg = g & 511;
    const float4 v0 = *(const float4*)(W + (long)e * DK + kg * 8);
    const float4 v1 = *(const float4*)(W + (long)e * DK + kg * 8 + 4);
    float xx[8] = {v0.x, v0.y, v0.z, v0.w, v1.x, v1.y, v1.z, v1.w};
    uint4 pl[3];
    split3(xx, pl);
    const int ks = kg >> 2;
    const int l  = (e & 15) | ((kg & 3) << 4);
    const int et = e >> 4;
#pragma unroll
    for (int p = 0; p < 3; ++p)
        WF[((ks * 4 + et) * 3 + p) * 64 + l] = pl[p];
}

// Main: 256 blocks x 64 rows, 8 waves = eh(2) x rq(4). NO VMEM in the inner
// loop: A and B both via ds_read_b128 (fine-grained lgkmcnt -- the path the
// compiler schedules well); all global traffic is global_load_lds staging
// with ONE drain per stage. This removes the allocator-serialized VMEM
// convoy that pinned R11-R16 at ~114us.
__global__ __launch_bounds__(512) void token_router(
    const float* __restrict__ x, const uint4* __restrict__ WF,
    float* __restrict__ out)
{
    __shared__ float xs[2 * BM * 128];       // 64 KB X f32, dbuf, swizzled
    __shared__ uint4 bs[4 * 12 * 64];        // 48 KB B-fragment slice, single-buf
    __shared__ float lg[BM * 68 + 2 * BM];   // 17.9 KB

    const int tid  = threadIdx.x;
    const int wv   = tid >> 6;
    const int lane = tid & 63;
    const int eh   = wv & 1;
    const int rq   = wv >> 1;
    const long rowbase = (long)blockIdx.x * BM;

    // ---- X staging: wave wv stages row-pairs wv*8 .. wv*8+7 (4 insts) ----
    // inst rp covers rows {2rp, 2rp+1}, lane l -> row 2rp+(l>>5), kq l&31.
    // LDS slot (r, sq) holds global kq = sq ^ (r&7)  (pre-swizzled source).
    const int xr  = (lane >> 5);             // 0/1 within pair
    const int xkq = lane & 31;
    // per-inst source offsets computed in-loop (kbase varies per stage)

    // ---- B staging: wave wv stages insts wv*6 .. wv*6+5 ----

    // A-frag read coords
    const int rl   = rq * 16 + (lane & 15);          // row in tile
    const int o2   = (lane >> 4) * 2;                // first k-quad in octet
    const int rsw  = rl & 7;
    const float* arow = xs + rl * 128;               // + buf*8192 + slot*4

    f32x4 acc0 = {0.f, 0.f, 0.f, 0.f};
    f32x4 acc1 = {0.f, 0.f, 0.f, 0.f};

    // prologue: stage X(0) and B(0)
#pragma unroll
    for (int i = 0; i < 4; ++i) {
        const int rp = wv * 4 + i;
        const int r  = 2 * rp + xr;
        gl_lds16(x + (rowbase + r) * (long)DK + ((xkq ^ (r & 7)) << 2),
                 xs + rp * 256 + lane * 4);
    }
#pragma unroll
    for (int i = 0; i < 6; ++i) {
        const int bi = wv * 6 + i;
        gl_lds16(WF + bi * 64 + lane, bs + bi * 64 + lane);
    }
    __syncthreads();

    for (int s = 0; s < NSTG; ++s) {
        const int buf = (s & 1) * 8192;
        // issue X(s+1) into the other buffer (drained at the next barrier)
        if (s + 1 < NSTG) {
            const long kb = (long)(s + 1) * 128;
            const int nb = (buf ^ 8192);
#pragma unroll
            for (int i = 0; i < 4; ++i) {
                const int rp = wv * 4 + i;
                const int r  = 2 * rp + xr;
                gl_lds16(x + (rowbase + r) * (long)DK + kb + ((xkq ^ (r & 7)) << 2),
                         xs + nb + rp * 256 + lane * 4);
            }
        }
        // compute 4 k-groups from xs[buf], bs
#pragma unroll
        for (int ksl = 0; ksl < 4; ++ksl) {
            uint4 b0[3], b1[3];
#pragma unroll
            for (int p = 0; p < 3; ++p) {
                b0[p] = bs[ksl * 768 + ((2 * eh + 0) * 3 + p) * 64 + lane];
                b1[p] = bs[ksl * 768 + ((2 * eh + 1) * 3 + p) * 64 + lane];
            }
            const int q0 = ksl * 8 + o2;
            const float4 alo = *(const float4*)(arow + buf + ((q0 ^ rsw) << 2));
            const float4 ahi = *(const float4*)(arow + buf + (((q0 + 1) ^ rsw) << 2));
            float xx[8] = {alo.x, alo.y, alo.z, alo.w, ahi.x, ahi.y, ahi.z, ahi.w};
            uint4 pl[3];
            split3(xx, pl);
            const bf16x8 A0 = __builtin_bit_cast(bf16x8, pl[0]);
            const bf16x8 A1 = __builtin_bit_cast(bf16x8, pl[1]);
            const bf16x8 A2 = __builtin_bit_cast(bf16x8, pl[2]);
            {
                const bf16x8 B0 = __builtin_bit_cast(bf16x8, b0[0]);
                const bf16x8 B1 = __builtin_bit_cast(bf16x8, b0[1]);
                const bf16x8 B2 = __builtin_bit_cast(bf16x8, b0[2]);
                acc0 = __builtin_amdgcn_mfma_f32_16x16x32_bf16(A0, B0, acc0, 0, 0, 0);
                acc0 = __builtin_amdgcn_mfma_f32_16x16x32_bf16(A0, B1, acc0, 0, 0, 0);
                acc0 = __builtin_amdgcn_mfma_f32_16x16x32_bf16(A1, B0, acc0, 0, 0, 0);
                acc0 = __builtin_amdgcn_mfma_f32_16x16x32_bf16(A1, B1, acc0, 0, 0, 0);
                acc0 = __builtin_amdgcn_mfma_f32_16x16x32_bf16(A0, B2, acc0, 0, 0, 0);
                acc0 = __builtin_amdgcn_mfma_f32_16x16x32_bf16(A2, B0, acc0, 0, 0, 0);
            }
            {
                const bf16x8 B0 = __builtin_bit_cast(bf16x8, b1[0]);
                const bf16x8 B1 = __builtin_bit_cast(bf16x8, b1[1]);
                const bf16x8 B2 = __builtin_bit_cast(bf16x8, b1[2]);
                acc1 = __builtin_amdgcn_mfma_f32_16x16x32_bf16(A0, B0, acc1, 0, 0, 0);
                acc1 = __builtin_amdgcn_mfma_f32_16x16x32_bf16(A0, B1, acc1, 0, 0, 0);
                acc1 = __builtin_amdgcn_mfma_f32_16x16x32_bf16(A1, B0, acc1, 0, 0, 0);
                acc1 = __builtin_amdgcn_mfma_f32_16x16x32_bf16(A1, B1, acc1, 0, 0, 0);
                acc1 = __builtin_amdgcn_mfma_f32_16x16x32_bf16(A0, B2, acc1, 0, 0, 0);
                acc1 = __builtin_amdgcn_mfma_f32_16x16x32_bf16(A2, B0, acc1, 0, 0, 0);
            }
        }
        __syncthreads();                 // everyone done reading bs
        if (s + 1 < NSTG) {
            const uint4* wfn = WF + (long)(s + 1) * 3072;
#pragma unroll
            for (int i = 0; i < 6; ++i) {
                const int bi = wv * 6 + i;
                gl_lds16(wfn + bi * 64 + lane, bs + bi * 64 + lane);
            }
        }
        __syncthreads();                 // drain staging (single stall/stage)
    }

    // ---- logits to LDS (C/D: col = lane&15, row = (lane>>4)*4 + jj) ----
#pragma unroll
    for (int jj = 0; jj < 4; ++jj) {
        const int row = rq * 16 + (lane >> 4) * 4 + jj;
        lg[row * 68 + (2 * eh + 0) * 16 + (lane & 15)] = acc0[jj];
        lg[row * 68 + (2 * eh + 1) * 16 + (lane & 15)] = acc1[jj];
    }
    __syncthreads();

    // ---- per-row softmax stats + stable top-2 (one thread per row) ----
    float* rowm   = lg + BM * 68;
    float* rowinv = rowm + BM;
    if (tid < BM) {
        const int row = tid;
        float m = -3.4e38f;
        for (int e = 0; e < NE; ++e) m = fmaxf(m, lg[row * 68 + e]);
        float s = 0.f;
        float v1 = -1.f, v2 = -1.f;
        int   i1 = 0,    i2 = 0;
        for (int e = 0; e < NE; ++e) {
            const float p = __expf(lg[row * 68 + e] - m);
            s += p;
            if (p > v1)      { v2 = v1; i2 = i1; v1 = p; i1 = e; }
            else if (p > v2) { v2 = p; i2 = e; }
        }
        const float inv = 1.f / s;
        rowm[row]   = m;
        rowinv[row] = inv;
        const long grow = rowbase + row;
        const float p1 = v1 * inv, p2 = v2 * inv;
        const float dn = p1 + p2 + 1e-9f;
        out[NIDX + grow * 2 + 0] = (float)i1;
        out[NIDX + grow * 2 + 1] = (float)i2;
        out[NWTS + grow * 2 + 0] = p1 / dn;
        out[NWTS + grow * 2 + 1] = p2 / dn;
    }
    __syncthreads();

    // ---- probs write: 512 threads x 8 floats, coalesced ----
    {
        const int row = tid >> 3;
        const int e0  = (tid & 7) << 3;
        const float m = rowm[row], inv = rowinv[row];
        const long grow = rowbase + row;
        const float4 l4a = *reinterpret_cast<const float4*>(&lg[row * 68 + e0]);
        const float4 l4b = *reinterpret_cast<const float4*>(&lg[row * 68 + e0 + 4]);
        float4 p0, p1;
        p0.x = __expf(l4a.x - m) * inv;
        p0.y = __expf(l4a.y - m) * inv;
        p0.z = __expf(l4a.z - m) * inv;
        p0.w = __expf(l4a.w - m) * inv;
        p1.x = __expf(l4b.x - m) * inv;
        p1.y = __expf(l4b.y - m) * inv;
        p1.z = __expf(l4b.z - m) * inv;
        p1.w = __expf(l4b.w - m) * inv;
        *reinterpret_cast<float4*>(&out[grow * (long)NE + e0])     = p0;
        *reinterpret_cast<float4*>(&out[grow * (long)NE + e0 + 4]) = p1;
    }
}

extern "C" void kernel_launch(void* const* d_in, const int* in_sizes, int n_in,
                              void* d_out, int out_size, void* d_ws, size_t ws_size,
                              hipStream_t stream) {
    const float* x = (const float*)d_in[0];
    const float* W = (const float*)d_in[1];
    float* out = (float*)d_out;
    uint4* WF  = (uint4*)d_ws;   // 1.5 MB fragment-ordered W planes

    w_prep<<<dim3(128), dim3(256), 0, stream>>>(W, WF);
    token_router<<<dim3(BT / BM), dim3(512), 0, stream>>>(x, WF, out);
}